// Round 1
// baseline (1139.349 us; speedup 1.0000x reference)
//
#include <hip/hip_runtime.h>
#include <hip/hip_bf16.h>

// GRU scan with sparse resets. T=1024, B=256, D=128, H=128.
// Decomposition: recurrence is independent per batch element ->
// 1 block per batch element (256 blocks ~= 1/CU), 512 threads.
// Weights register-resident as packed f16 pairs; h carried in f32;
// input projection fused (no gi materialization, no workspace use).

#define T_STEPS 1024
#define B_SZ 256
#define D_SZ 128
#define H_SZ 128

typedef _Float16 h2 __attribute__((ext_vector_type(2)));

__device__ __forceinline__ float dot2f(h2 a, h2 b, float c) {
#if __has_builtin(__builtin_amdgcn_fdot2)
  return __builtin_amdgcn_fdot2(a, b, c, false);
#else
  return c + (float)a.x * (float)b.x + (float)a.y * (float)b.y;
#endif
}

__global__ __launch_bounds__(512, 2)
void gru_scan_kernel(const float* __restrict__ seq,
                     const int* __restrict__ resets,
                     const float* __restrict__ h0,
                     const float* __restrict__ Wi,
                     const float* __restrict__ Wh,
                     const float* __restrict__ bh,
                     float* __restrict__ out) {
  const int b = blockIdx.x;
  const int tid = threadIdx.x;
  const int g = tid >> 7;     // k-group 0..3 (k in [32g, 32g+32))
  const int l = tid & 127;    // column within each gate / hidden index

  __shared__ int   rst[T_STEPS];          // reset flags for this batch elem
  __shared__ float part[6][4][H_SZ];      // partial sums: 6 channels x 4 k-groups
  __shared__ float bhs[3 * H_SZ];
  __shared__ h2    x16[D_SZ / 2];         // current x as f16 pairs
  __shared__ h2    hh16[H_SZ / 2];        // current h as f16 pairs
  __shared__ h2    h016[H_SZ / 2];        // initial carry as f16 pairs
  __shared__ float h32[H_SZ];             // current h in f32
  __shared__ float h032[H_SZ];            // initial carry in f32

  // ---- prologue: stage per-block constants ----
  for (int i = tid; i < T_STEPS; i += 512) rst[i] = resets[(size_t)i * B_SZ + b];
  if (tid < 3 * H_SZ) bhs[tid] = bh[tid];
  if (tid < H_SZ) {
    float v = h0[(size_t)b * H_SZ + tid];
    h32[tid] = v;
    h032[tid] = v;
    ((_Float16*)hh16)[tid] = (_Float16)v;
    ((_Float16*)h016)[tid] = (_Float16)v;
    float x0 = seq[((size_t)0 * B_SZ + b) * D_SZ + tid];
    ((_Float16*)x16)[tid] = (_Float16)x0;
  }

  // ---- weights -> registers (f16 pairs along k) ----
  // thread (g,l) owns columns {l, 128+l, 256+l} for k in [32g, 32g+32)
  h2 wiR[3][16], whR[3][16];
#pragma unroll
  for (int c = 0; c < 3; c++) {
    const int col = c * H_SZ + l;
#pragma unroll
    for (int kk2 = 0; kk2 < 16; kk2++) {
      const int k0 = g * 32 + kk2 * 2;
      float a0 = Wi[(size_t)k0 * 384 + col];
      float a1 = Wi[(size_t)(k0 + 1) * 384 + col];
      h2 wa; wa.x = (_Float16)a0; wa.y = (_Float16)a1;
      wiR[c][kk2] = wa;
      float b0 = Wh[(size_t)k0 * 384 + col];
      float b1 = Wh[(size_t)(k0 + 1) * 384 + col];
      h2 wb; wb.x = (_Float16)b0; wb.y = (_Float16)b1;
      whR[c][kk2] = wb;
    }
  }

  // ---- x prefetch registers (threads 0..127), depth 2 ----
  float xA = 0.f, xB = 0.f;
  if (tid < D_SZ) {
    xA = seq[((size_t)1 * B_SZ + b) * D_SZ + tid];
    xB = seq[((size_t)2 * B_SZ + b) * D_SZ + tid];
  }

  __syncthreads();

  float* ys = out + (size_t)B_SZ * H_SZ;  // out = [final_carry (B,H)] ++ [ys (T,B,H)]

#pragma unroll 1
  for (int t = 0; t < T_STEPS; t++) {
    const int rf = rst[t];
    const h2* hsrc = rf ? h016 : hh16;

    float pir = 0.f, piz = 0.f, pin = 0.f, phr = 0.f, phz = 0.f, phn = 0.f;
#pragma unroll
    for (int kk2 = 0; kk2 < 16; kk2++) {
      h2 xv = x16[g * 16 + kk2];
      h2 hv = hsrc[g * 16 + kk2];
      pir = dot2f(xv, wiR[0][kk2], pir);
      piz = dot2f(xv, wiR[1][kk2], piz);
      pin = dot2f(xv, wiR[2][kk2], pin);
      phr = dot2f(hv, whR[0][kk2], phr);
      phz = dot2f(hv, whR[1][kk2], phz);
      phn = dot2f(hv, whR[2][kk2], phn);
    }
    part[0][g][l] = pir; part[1][g][l] = piz; part[2][g][l] = pin;
    part[3][g][l] = phr; part[4][g][l] = phz; part[5][g][l] = phn;
    __syncthreads();

    if (tid < H_SZ) {
      float ir = 0.f, iz = 0.f, inn = 0.f, hr = 0.f, hz = 0.f, hn = 0.f;
#pragma unroll
      for (int gg = 0; gg < 4; gg++) {
        ir  += part[0][gg][tid];
        iz  += part[1][gg][tid];
        inn += part[2][gg][tid];
        hr  += part[3][gg][tid];
        hz  += part[4][gg][tid];
        hn  += part[5][gg][tid];
      }
      float ar = ir + hr + bhs[tid];
      float az = iz + hz + bhs[H_SZ + tid];
      float ah = hn + bhs[2 * H_SZ + tid];     // h_n incl. bias, scaled by r inside tanh
      float r = 1.f / (1.f + __expf(-ar));
      float z = 1.f / (1.f + __expf(-az));
      float ta = inn + r * ah;
      ta = fminf(fmaxf(ta, -15.f), 15.f);      // avoid inf/inf NaN in tanh
      float e2 = __expf(2.f * ta);
      float n = (e2 - 1.f) / (e2 + 1.f);
      float hu = rf ? h032[tid] : h32[tid];    // post-reset carry for the z*h term
      float hnew = n + z * (hu - n);

      ys[((size_t)t * B_SZ + b) * H_SZ + tid] = hnew;
      h32[tid] = hnew;
      ((_Float16*)hh16)[tid] = (_Float16)hnew;
      if (t == T_STEPS - 1) out[(size_t)b * H_SZ + tid] = hnew;

      // rotate x prefetch: expose seq[t+1] for next step, issue seq[t+3]
      ((_Float16*)x16)[tid] = (_Float16)xA;
      xA = xB;
      int tt = t + 3;
      if (tt > T_STEPS - 1) tt = T_STEPS - 1;
      xB = seq[((size_t)tt * B_SZ + b) * D_SZ + tid];
    }
    __syncthreads();
  }
}

extern "C" void kernel_launch(void* const* d_in, const int* in_sizes, int n_in,
                              void* d_out, int out_size, void* d_ws, size_t ws_size,
                              hipStream_t stream) {
  const float* seq    = (const float*)d_in[0];
  const int*   resets = (const int*)d_in[1];
  const float* h0     = (const float*)d_in[2];
  const float* Wi     = (const float*)d_in[3];
  const float* Wh     = (const float*)d_in[4];
  const float* bh     = (const float*)d_in[5];
  (void)in_sizes; (void)n_in; (void)d_ws; (void)ws_size; (void)out_size;

  gru_scan_kernel<<<B_SZ, 512, 0, stream>>>(seq, resets, h0, Wi, Wh, bh, (float*)d_out);
}

// Round 2
// 830.619 us; speedup vs baseline: 1.3717x; 1.3717x over previous
//
#include <hip/hip_runtime.h>
#include <hip/hip_bf16.h>

// GRU scan with sparse resets. T=1024, B=256, D=128, H=128.
// One block per batch element (256 blocks = 1/CU), 512 threads = 8 waves.
// Wave w owns output columns c = w*16 + (lane&15); g = lane>>4 is the
// k-group (k in [32g,32g+32)). k-reduction via __shfl_xor butterfly
// (in-wave), so there is NO LDS reduction phase and only ONE barrier
// per step (ping-pong x/h buffers). Weights register-resident as f16
// pairs; reset folded into the carry write; h carried in f32 register.

#define T_STEPS 1024
#define B_SZ 256
#define D_SZ 128
#define H_SZ 128

typedef _Float16 h2 __attribute__((ext_vector_type(2)));
typedef _Float16 h8 __attribute__((ext_vector_type(8)));

union U8 { h8 v; h2 p[4]; };

__device__ __forceinline__ float dot2f(h2 a, h2 b, float c) {
#if __has_builtin(__builtin_amdgcn_fdot2)
  return __builtin_amdgcn_fdot2(a, b, c, false);
#else
  return c + (float)a.x * (float)b.x + (float)a.y * (float)b.y;
#endif
}

__device__ __forceinline__ float fastrcp(float x) {
#if __has_builtin(__builtin_amdgcn_rcpf)
  return __builtin_amdgcn_rcpf(x);
#else
  return 1.0f / x;
#endif
}

__global__ __launch_bounds__(512, 2)
void gru_scan_kernel(const float* __restrict__ seq,
                     const int* __restrict__ resets,
                     const float* __restrict__ h0,
                     const float* __restrict__ Wi,
                     const float* __restrict__ Wh,
                     const float* __restrict__ bh,
                     float* __restrict__ out) {
  const int b = blockIdx.x;
  const int tid = threadIdx.x;
  const int w = tid >> 6;          // wave 0..7
  const int lane = tid & 63;
  const int c = (w << 4) | (lane & 15);  // output column 0..127
  const int g = lane >> 4;               // k-group 0..3

  __shared__ int rst[T_STEPS];
  __shared__ __align__(16) _Float16 x16[2][D_SZ];   // ping-pong x (f16)
  __shared__ __align__(16) _Float16 hh16[2][H_SZ];  // ping-pong h_eff (f16)

  // ---- prologue ----
  for (int i = tid; i < T_STEPS; i += 512) rst[i] = resets[(size_t)i * B_SZ + b];

  // weights -> registers: thread (c,g) holds k in [32g,32g+32) of columns
  // {c, 128+c, 256+c} for both Wi and Wh, as f16 pairs along k.
  h2 wiR[3][16], whR[3][16];
  const int k0 = g * 32;
#pragma unroll
  for (int ch = 0; ch < 3; ch++) {
    const int col = ch * H_SZ + c;
#pragma unroll
    for (int j = 0; j < 16; j++) {
      const int k = k0 + 2 * j;
      h2 wa; wa.x = (_Float16)Wi[(size_t)k * 384 + col];
             wa.y = (_Float16)Wi[(size_t)(k + 1) * 384 + col];
      wiR[ch][j] = wa;
      h2 wb; wb.x = (_Float16)Wh[(size_t)k * 384 + col];
             wb.y = (_Float16)Wh[(size_t)(k + 1) * 384 + col];
      whR[ch][j] = wb;
    }
  }

  const float bhr = bh[c];
  const float bhz = bh[H_SZ + c];
  const float bhn = bh[2 * H_SZ + c];
  const float h0c = h0[(size_t)b * H_SZ + c];
  float hu = h0c;  // effective carry h_eff(t)[c], f32 (valid in all g-copies)

  if (tid < H_SZ) {
    hh16[0][tid] = (_Float16)h0[(size_t)b * H_SZ + tid];
    x16[0][tid]  = (_Float16)seq[((size_t)0 * B_SZ + b) * D_SZ + tid];
  }
  float xA = 0.f, xB = 0.f;
  if (tid < D_SZ) {
    xA = seq[((size_t)1 * B_SZ + b) * D_SZ + tid];
    xB = seq[((size_t)2 * B_SZ + b) * D_SZ + tid];
  }
  __syncthreads();

  float* ys = out + (size_t)B_SZ * H_SZ;  // out = [final_carry] ++ [ys]

#pragma unroll 1
  for (int t = 0; t < T_STEPS; t++) {
    const int p = t & 1;
    const int rnext = rst[(t + 1) & (T_STEPS - 1)];  // reset flag for step t+1

    const h8* xb = (const h8*)&x16[p][g * 32];
    const h8* hb = (const h8*)&hh16[p][g * 32];
    float cr = 0.f, cz = 0.f, ci = 0.f, chn = 0.f;
#pragma unroll
    for (int q = 0; q < 4; q++) {
      U8 ux, uh; ux.v = xb[q]; uh.v = hb[q];
#pragma unroll
      for (int j = 0; j < 4; j++) {
        const int idx = q * 4 + j;
        cr  = dot2f(ux.p[j], wiR[0][idx], cr);   // i_r partial
        cz  = dot2f(ux.p[j], wiR[1][idx], cz);   // i_z partial
        ci  = dot2f(ux.p[j], wiR[2][idx], ci);   // i_n partial
        cr  = dot2f(uh.p[j], whR[0][idx], cr);   // + h_r partial
        cz  = dot2f(uh.p[j], whR[1][idx], cz);   // + h_z partial
        chn = dot2f(uh.p[j], whR[2][idx], chn);  // h_n partial
      }
    }
    // butterfly reduce over g (lane^16, lane^32): all lanes get full sums
    cr  += __shfl_xor(cr, 16, 64);
    cz  += __shfl_xor(cz, 16, 64);
    ci  += __shfl_xor(ci, 16, 64);
    chn += __shfl_xor(chn, 16, 64);
    cr  += __shfl_xor(cr, 32, 64);
    cz  += __shfl_xor(cz, 32, 64);
    ci  += __shfl_xor(ci, 32, 64);
    chn += __shfl_xor(chn, 32, 64);

    const float ar = cr + bhr;
    const float az = cz + bhz;
    const float ah = chn + bhn;
    const float r = fastrcp(1.f + __expf(-ar));
    const float z = fastrcp(1.f + __expf(-az));
    float ta = ci + r * ah;
    ta = fminf(fmaxf(ta, -15.f), 15.f);
    const float e2 = __expf(2.f * ta);
    const float n = (e2 - 1.f) * fastrcp(e2 + 1.f);
    const float hnew = n + z * (hu - n);
    const float hunew = rnext ? h0c : hnew;  // effective carry for step t+1
    hu = hunew;

    if (g == 0) {
      ys[((size_t)t * B_SZ + b) * H_SZ + c] = hnew;
      hh16[p ^ 1][c] = (_Float16)hunew;
      if (t == T_STEPS - 1) out[(size_t)b * H_SZ + c] = hnew;
    }
    if (tid < D_SZ) {
      x16[p ^ 1][tid] = (_Float16)xA;  // expose seq[t+1]
      xA = xB;
      int tt = t + 3; if (tt > T_STEPS - 1) tt = T_STEPS - 1;
      xB = seq[((size_t)tt * B_SZ + b) * D_SZ + tid];
    }
    __syncthreads();
  }
}

extern "C" void kernel_launch(void* const* d_in, const int* in_sizes, int n_in,
                              void* d_out, int out_size, void* d_ws, size_t ws_size,
                              hipStream_t stream) {
  const float* seq    = (const float*)d_in[0];
  const int*   resets = (const int*)d_in[1];
  const float* h0     = (const float*)d_in[2];
  const float* Wi     = (const float*)d_in[3];
  const float* Wh     = (const float*)d_in[4];
  const float* bh     = (const float*)d_in[5];
  (void)in_sizes; (void)n_in; (void)d_ws; (void)ws_size; (void)out_size;

  gru_scan_kernel<<<B_SZ, 512, 0, stream>>>(seq, resets, h0, Wi, Wh, bh, (float*)d_out);
}